// Round 7
// baseline (267.119 us; speedup 1.0000x reference)
//
#include <hip/hip_runtime.h>
#include <hip/hip_bf16.h>
#include <cmath>

#define N_NODES 50000
#define N_EDGES 800000
#define FEAT_BLOCKS 782            /* 3125 M-tiles / 4 waves, rounded up */
#define HIST_BLOCKS 1563
#define KA_GRID (FEAT_BLOCKS + HIST_BLOCKS)
#define SCAN_BLOCKS 49             /* ceil(50000/1024) */
#define WC_BLOCKS 30               /* ceil(192*160/1024) */

typedef __attribute__((ext_vector_type(8))) short bf16x8;
typedef __attribute__((ext_vector_type(4))) float f32x4;

__device__ inline short bfbits(float x) {
    __hip_bfloat16 t = __float2bfloat16(x);
    return *reinterpret_cast<short*>(&t);
}

// ---------------------------------------------------------------------------
// K_A (fused): blocks [0,782): GAT projection via MFMA (Wcomb built in LDS,
// h converted inline, stores staged through LDS for dwordx4 coalescing).
// blocks [782,2345): in-degree histogram + per-edge rank (grid-stride).
// ---------------------------------------------------------------------------
__global__ __launch_bounds__(256) void k_feat_hist(
        const float* __restrict__ h, const float* __restrict__ Wg,
        const float* __restrict__ al, const float* __restrict__ ar,
        const int* __restrict__ dst, int* __restrict__ counts,
        int* __restrict__ rank, __hip_bfloat16* __restrict__ feat,
        float* __restrict__ el, float* __restrict__ er) {
    const int t = threadIdx.x;
    if (blockIdx.x >= FEAT_BLOCKS) {
        // ---- histogram role ----
        for (int e = (blockIdx.x - FEAT_BLOCKS) * 256 + t; e < N_EDGES;
             e += HIST_BLOCKS * 256)
            rank[e] = atomicAdd(&counts[dst[e]], 1);
        return;
    }
    // ---- feat role ----
    __shared__ __hip_bfloat16 Wl[144 * 40];        // B matrix, padded stride 40
    __shared__ __hip_bfloat16 sbuf[4][16][136];    // per-wave store staging
    // build Wcomb: rows 0..127 = Wg^T (coalesced read, transposed LDS write)
#pragma unroll
    for (int it = 0; it < 16; ++it) {
        const int idx = it * 256 + t;              // idx = k*128 + row
        const int k = idx >> 7, row = idx & 127;
        Wl[row * 40 + k] = __float2bfloat16(Wg[idx]);
    }
    {   // rows 128..135: fused attn_l/attn_r dot columns; rows 136..143: zero
        const int row8 = t >> 5, k = t & 31;
        const int hd = row8 & 3;
        const float* a = (row8 < 4) ? (al + hd * 32) : (ar + hd * 32);
        const float* w = Wg + k * 128 + hd * 32;
        float v = 0.f;
#pragma unroll
        for (int f = 0; f < 32; ++f) v = fmaf(w[f], a[f], v);
        Wl[(128 + row8) * 40 + k] = __float2bfloat16(v);
        Wl[(136 + row8) * 40 + k] = __float2bfloat16(0.f);
    }
    __syncthreads();
    const int lane = t & 63, wave = t >> 6;
    const int li = lane & 15, quad = lane >> 4;
    const int mt = blockIdx.x * 4 + wave;
    if (mt >= N_NODES / 16) return;
    const int m_base = mt * 16;
    // A fragment: row m_base+li, k = quad*8..quad*8+7, converted inline
    bf16x8 a;
    {
        const float4* hp = (const float4*)(h + (size_t)(m_base + li) * 32 + quad * 8);
        const float4 f0 = hp[0], f1 = hp[1];
        a[0] = bfbits(f0.x); a[1] = bfbits(f0.y); a[2] = bfbits(f0.z); a[3] = bfbits(f0.w);
        a[4] = bfbits(f1.x); a[5] = bfbits(f1.y); a[6] = bfbits(f1.z); a[7] = bfbits(f1.w);
    }
    f32x4 acc[9];
#pragma unroll
    for (int j = 0; j < 9; ++j) acc[j] = (f32x4){0.f, 0.f, 0.f, 0.f};
#pragma unroll
    for (int j = 0; j < 9; ++j) {
        const bf16x8 b = *(const bf16x8*)(&Wl[(j * 16 + li) * 40 + quad * 8]);
        acc[j] = __builtin_amdgcn_mfma_f32_16x16x32_bf16(a, b, acc[j], 0, 0, 0);
    }
    // stage feat tiles (0..7) into LDS, then coalesced dwordx4 stores
#pragma unroll
    for (int j = 0; j < 8; ++j)
#pragma unroll
        for (int i = 0; i < 4; ++i)
            sbuf[wave][quad * 4 + i][j * 16 + li] = __float2bfloat16(acc[j][i]);
    __builtin_amdgcn_wave_barrier();
#pragma unroll
    for (int rep = 0; rep < 4; ++rep) {
        const int row = rep * 4 + quad;
        const bf16x8 v = *(const bf16x8*)(&sbuf[wave][row][li * 8]);
        *(bf16x8*)(feat + (size_t)(m_base + row) * 128 + li * 8) = v;
    }
    if (li < 8) {
#pragma unroll
        for (int i = 0; i < 4; ++i) {
            const int m = m_base + quad * 4 + i;
            if (li < 4) el[m * 4 + li] = acc[8][i];
            else        er[m * 4 + (li - 4)] = acc[8][i];
        }
    }
}

// ---------------------------------------------------------------------------
// K_B (fused): blocks [0,49): single-pass chained exclusive scan of counts ->
// offsets (decoupled lookback; all blocks co-resident: 79 blocks << capacity).
// blocks [49,79): Wc[192][160] bf16 block-diag GRU weight prep.
// ---------------------------------------------------------------------------
__global__ __launch_bounds__(1024) void k_scan_wc(
        const int* __restrict__ counts, int* __restrict__ offsets,
        int* __restrict__ flags, int* __restrict__ pref,
        const float* __restrict__ Wih, const float* __restrict__ Whh,
        __hip_bfloat16* __restrict__ Wc) {
    const int t = threadIdx.x;
    const int b = blockIdx.x;
    if (b >= SCAN_BLOCKS) {
        const int idx = (b - SCAN_BLOCKS) * 1024 + t;
        if (idx < 192 * 160) {
            const int r = idx / 160, k = idx - r * 160;
            float v = 0.f;
            if (r < 96) { if (k < 128) v = Wih[r * 128 + k]; }
            else        { if (k >= 128) v = Whh[(r - 96) * 32 + (k - 128)]; }
            Wc[idx] = __float2bfloat16(v);
        }
        return;
    }
    __shared__ int wtot[16];
    __shared__ int base_s;
    const int wave = t >> 6, lane = t & 63;
    const int idx = b * 1024 + t;
    const int v = (idx < N_NODES) ? counts[idx] : 0;
    int x = v;
#pragma unroll
    for (int m = 1; m < 64; m <<= 1) {
        const int y = __shfl_up(x, m, 64);
        if (lane >= m) x += y;
    }
    if (lane == 63) wtot[wave] = x;
    __syncthreads();
    if (t == 0) {
        int s = 0;
#pragma unroll
        for (int i = 0; i < 16; ++i) { const int tmp = wtot[i]; wtot[i] = s; s += tmp; }
        int base = 0;
        if (b > 0) {
            while (__hip_atomic_load(&flags[b - 1], __ATOMIC_ACQUIRE,
                                     __HIP_MEMORY_SCOPE_AGENT) == 0)
                __builtin_amdgcn_s_sleep(1);
            base = __hip_atomic_load(&pref[b - 1], __ATOMIC_RELAXED,
                                     __HIP_MEMORY_SCOPE_AGENT);
        }
        __hip_atomic_store(&pref[b], base + s, __ATOMIC_RELAXED,
                           __HIP_MEMORY_SCOPE_AGENT);
        __hip_atomic_store(&flags[b], 1, __ATOMIC_RELEASE,
                           __HIP_MEMORY_SCOPE_AGENT);
        base_s = base;
        if (b == SCAN_BLOCKS - 1) offsets[N_NODES] = N_EDGES;
    }
    __syncthreads();
    if (idx < N_NODES) offsets[idx] = base_s + wtot[wave] + x - v;
}

// ---------------------------------------------------------------------------
// K_C: scatter src ids into dst-sorted order — atomic-free (offsets + rank)
// ---------------------------------------------------------------------------
__global__ __launch_bounds__(1024) void k_scatter(
        const int* __restrict__ src, const int* __restrict__ dst,
        const int* __restrict__ offsets, const int* __restrict__ rank,
        int* __restrict__ srcs) {
    const int e = blockIdx.x * 1024 + threadIdx.x;
    if (e < N_EDGES) srcs[offsets[dst[e]] + rank[e]] = src[e];
}

// ---------------------------------------------------------------------------
// K_D (fused aggr + GRU): block = 4 waves = 16 nodes = one GRU M-tile.
// Phase 1: wave w aggregates nodes w*4..w*4+3 into LDS xh_tile (8-deep
//          batched gather; one wave reads a full 256 B bf16 feat row).
// Phase 2: GRU GEMM [gi|gh](16,192) = xh_tile(16,160) @ Wc^T.
// ---------------------------------------------------------------------------
__global__ __launch_bounds__(256) void k_aggr_gru(
        const int* __restrict__ offsets, const int* __restrict__ srcs,
        const __hip_bfloat16* __restrict__ feat,
        const float* __restrict__ el, const float* __restrict__ er,
        const float* __restrict__ h, const __hip_bfloat16* __restrict__ Wc,
        const float* __restrict__ bih, const float* __restrict__ bhh,
        float* __restrict__ out) {
    __shared__ __hip_bfloat16 xh_tile[16][160];   // 5 KB
    __shared__ int   sl_s[4][64];                 // 1 KB
    __shared__ float eel_s[4][256];               // 4 KB
    __shared__ float ex[2][3][16][16];            // 6 KB gh exchange
    const int wave = threadIdx.x >> 6;
    const int lane = threadIdx.x & 63;
    int*   sl  = sl_s[wave];
    float* eel = eel_s[wave];
    const int hs = lane & 3;
    const int hc = lane >> 4;
    const int mbase = blockIdx.x * 16;

    // ---- phase 1 ----
    for (int u = 0; u < 4; ++u) {
        const int row = wave * 4 + u;
        const int n = mbase + row;
        const float ern = er[n * 4 + hs];
        const int start = offsets[n], end = offsets[n + 1];
        float ax = 0.f, ay = 0.f, psum = 0.f;
        for (int chunk = start; chunk < end; chunk += 64) {
            const int cnt = min(64, end - chunk);
            if (lane < cnt) sl[lane] = srcs[chunk + lane];
            __builtin_amdgcn_wave_barrier();
#pragma unroll
            for (int p = 0; p < 4; ++p) {
                const int j = p * 64 + lane;       // j&3 == lane&3
                if (j < cnt * 4) {
                    const int s = sl[j >> 2];
                    float v = el[s * 4 + hs] + ern;
                    v = v > 0.f ? v : 0.2f * v;    // leaky_relu(0.2)
                    const float e = expf(v);
                    eel[j] = e;
                    psum += e;
                }
            }
            __builtin_amdgcn_wave_barrier();
            int i = 0;
            for (; i + 8 <= cnt; i += 8) {         // 8 rows in flight
                __hip_bfloat162 f[8];
                float w[8];
#pragma unroll
                for (int q = 0; q < 8; ++q) {
                    f[q] = ((const __hip_bfloat162*)(feat + (size_t)sl[i + q] * 128))[lane];
                    w[q] = eel[(i + q) * 4 + hc];
                }
#pragma unroll
                for (int q = 0; q < 8; ++q) {
                    ax = fmaf(w[q], __bfloat162float(f[q].x), ax);
                    ay = fmaf(w[q], __bfloat162float(f[q].y), ay);
                }
            }
            for (; i < cnt; ++i) {
                const __hip_bfloat162 f = ((const __hip_bfloat162*)(feat + (size_t)sl[i] * 128))[lane];
                const float w = eel[i * 4 + hc];
                ax = fmaf(w, __bfloat162float(f.x), ax);
                ay = fmaf(w, __bfloat162float(f.y), ay);
            }
            __builtin_amdgcn_wave_barrier();
        }
#pragma unroll
        for (int m = 4; m < 64; m <<= 1) psum += __shfl_xor(psum, m, 64);
        const float dn = __shfl(psum, hc, 64);
        const float inv = (end > start) ? 1.f / dn : 0.f;
        __hip_bfloat162 v2;
        v2.x = __float2bfloat16(ax * inv);
        v2.y = __float2bfloat16(ay * inv);
        ((__hip_bfloat162*)&xh_tile[row][0])[lane] = v2;
        if (lane < 32) xh_tile[row][128 + lane] = __float2bfloat16(h[(size_t)n * 32 + lane]);
    }
    __syncthreads();

    // ---- phase 2: GRU MFMA ----
    const int li = lane & 15, quad = lane >> 4;
    const int cb = wave >> 1;          // output col block
    const int ghrole = wave & 1;       // 0: gi tiles, 1: gh tiles
    bf16x8 a[5];
#pragma unroll
    for (int s = 0; s < 5; ++s)
        a[s] = *(const bf16x8*)((const char*)&xh_tile[0][0] + li * 320 + s * 64 + quad * 16);
    f32x4 acc[3];
#pragma unroll
    for (int g = 0; g < 3; ++g) {      // g: 0=r, 1=z, 2=n
        acc[g] = (f32x4){0.f, 0.f, 0.f, 0.f};
        const int j = g * 2 + cb + ghrole * 6;
        const bf16x8* bp = (const bf16x8*)(Wc + (size_t)(j * 16 + li) * 160 + quad * 8);
        acc[g] = __builtin_amdgcn_mfma_f32_16x16x32_bf16(a[0], bp[0],  acc[g], 0, 0, 0);
        acc[g] = __builtin_amdgcn_mfma_f32_16x16x32_bf16(a[1], bp[4],  acc[g], 0, 0, 0);
        acc[g] = __builtin_amdgcn_mfma_f32_16x16x32_bf16(a[2], bp[8],  acc[g], 0, 0, 0);
        acc[g] = __builtin_amdgcn_mfma_f32_16x16x32_bf16(a[3], bp[12], acc[g], 0, 0, 0);
        acc[g] = __builtin_amdgcn_mfma_f32_16x16x32_bf16(a[4], bp[16], acc[g], 0, 0, 0);
    }
    if (ghrole) {
#pragma unroll
        for (int g = 0; g < 3; ++g)
#pragma unroll
            for (int i = 0; i < 4; ++i)
                ex[cb][g][quad * 4 + i][li] = acc[g][i];
    }
    __syncthreads();
    if (!ghrole) {
        const int c = cb * 16 + li;
        const float bir = bih[c],      bhr = bhh[c];
        const float biz = bih[32 + c], bhz = bhh[32 + c];
        const float bin = bih[64 + c], bhn = bhh[64 + c];
#pragma unroll
        for (int i = 0; i < 4; ++i) {
            const int row = quad * 4 + i;
            const int m = mbase + row;
            const float gr = acc[0][i] + bir + ex[cb][0][row][li] + bhr;
            const float gz = acc[1][i] + biz + ex[cb][1][row][li] + bhz;
            const float gnn = acc[2][i] + bin;
            const float ghn = ex[cb][2][row][li] + bhn;
            const float r = 1.f / (1.f + expf(-gr));
            const float z = 1.f / (1.f + expf(-gz));
            const float nn = tanhf(gnn + r * ghn);
            const float hv = h[(size_t)m * 32 + c];
            const float hn = (1.f - z) * nn + z * hv;
            out[(size_t)m * 32 + c] = hn > 0.f ? hn : expm1f(hn);
        }
    }
}

extern "C" void kernel_launch(void* const* d_in, const int* in_sizes, int n_in,
                              void* d_out, int out_size, void* d_ws, size_t ws_size,
                              hipStream_t stream) {
    const float* h   = (const float*)d_in[0];
    const float* Wg  = (const float*)d_in[1];
    const float* al  = (const float*)d_in[2];
    const float* ar  = (const float*)d_in[3];
    const float* Wih = (const float*)d_in[4];
    const float* Whh = (const float*)d_in[5];
    const float* bih = (const float*)d_in[6];
    const float* bhh = (const float*)d_in[7];
    const int* src   = (const int*)d_in[8];
    const int* dst   = (const int*)d_in[9];
    float* out = (float*)d_out;

    // workspace layout (~22 MB)
    float* el = (float*)d_ws;                                 // N*4 f32
    float* er = el + (size_t)N_NODES * 4;                     // N*4 f32
    __hip_bfloat16* featb = (__hip_bfloat16*)(er + (size_t)N_NODES * 4); // N*128 bf16
    __hip_bfloat16* Wc    = featb + (size_t)N_NODES * 128;    // 192*160 bf16
    int* counts  = (int*)(Wc + 192 * 160);                    // N
    int* flags   = counts + N_NODES;                          // 64
    int* pref    = flags + 64;                                // 64
    int* offsets = pref + 64;                                 // N+1
    int* srcs    = offsets + N_NODES + 1;                     // E
    int* rank    = srcs + N_EDGES;                            // E

    // zero counts + flags + pref in one shot
    hipMemsetAsync(counts, 0, (N_NODES + 128) * sizeof(int), stream);

    k_feat_hist<<<KA_GRID, 256, 0, stream>>>(
        h, Wg, al, ar, dst, counts, rank, featb, el, er);
    k_scan_wc<<<SCAN_BLOCKS + WC_BLOCKS, 1024, 0, stream>>>(
        counts, offsets, flags, pref, Wih, Whh, Wc);
    k_scatter<<<(N_EDGES + 1023) / 1024, 1024, 0, stream>>>(
        src, dst, offsets, rank, srcs);
    k_aggr_gru<<<N_NODES / 16, 256, 0, stream>>>(
        offsets, srcs, featb, el, er, h, Wc, bih, bhh, out);
}

// Round 8
// 260.522 us; speedup vs baseline: 1.0253x; 1.0253x over previous
//
#include <hip/hip_runtime.h>
#include <hip/hip_bf16.h>
#include <cmath>

#define N_NODES 50000
#define N_EDGES 800000

#define PREP_WC   (192 * 160)                 /* 30720 */
#define PREP_WCB  (144 * 32)                  /* 4608  */
#define PREP_ITEMS (PREP_WC + PREP_WCB)       /* 35328 */
#define PREP_BLOCKS ((PREP_ITEMS + 255) / 256)  /* 138 */
#define HIST_BLOCKS (N_EDGES / 256)           /* 3125 exact */
#define SCAN_BLOCKS 49                        /* ceil(50000/1024) */

typedef __attribute__((ext_vector_type(8))) short bf16x8;
typedef __attribute__((ext_vector_type(4))) float f32x4;

__device__ inline short bfbits(float x) {
    __hip_bfloat16 t = __float2bfloat16(x);
    return *reinterpret_cast<short*>(&t);
}

// ---------------------------------------------------------------------------
// K1 (fused prep + hist): blocks [0,138): build Wc (GRU B, 192x160 block-diag)
// and Wcomb (GAT B, 144x32: Wg^T cols + fused attn dots). blocks [138,3263):
// in-degree histogram + per-edge rank. No redundant work: each item once.
// ---------------------------------------------------------------------------
__global__ __launch_bounds__(256) void k_prep_hist(
        const float* __restrict__ Wih, const float* __restrict__ Whh,
        const float* __restrict__ Wg, const float* __restrict__ al,
        const float* __restrict__ ar, const int* __restrict__ dst,
        __hip_bfloat16* __restrict__ Wc, __hip_bfloat16* __restrict__ Wcomb,
        int* __restrict__ counts, int* __restrict__ rank) {
    const int t = threadIdx.x;
    if (blockIdx.x >= PREP_BLOCKS) {
        const int e = (blockIdx.x - PREP_BLOCKS) * 256 + t;   // exact cover
        rank[e] = atomicAdd(&counts[dst[e]], 1);
        return;
    }
    int idx = blockIdx.x * 256 + t;
    if (idx < PREP_WC) {
        const int r = idx / 160, k = idx - r * 160;
        float v = 0.f;
        if (r < 96) { if (k < 128) v = Wih[r * 128 + k]; }
        else        { if (k >= 128) v = Whh[(r - 96) * 32 + (k - 128)]; }
        Wc[idx] = __float2bfloat16(v);
        return;
    }
    idx -= PREP_WC;
    if (idx < PREP_WCB) {
        const int row = idx >> 5, k = idx & 31;
        float v = 0.f;
        if (row < 128) {
            v = Wg[k * 128 + row];
        } else if (row < 136) {
            const int hd = (row - 128) & 3;
            const float* a = (row < 132) ? (al + hd * 32) : (ar + hd * 32);
            const float* w = Wg + k * 128 + hd * 32;
#pragma unroll
            for (int f = 0; f < 32; ++f) v = fmaf(w[f], a[f], v);
        }
        Wcomb[idx] = __float2bfloat16(v);
    }
}

// ---------------------------------------------------------------------------
// K2: GAT projection via MFMA. h converted f32->bf16 inline (no hb pass).
// Wcomb read from global (built once). feat stores staged via LDS -> dwordx4.
// Tiles 0..7 -> feat bf16; tile 8 -> el/er f32.
// ---------------------------------------------------------------------------
__global__ __launch_bounds__(256) void k_feat_mfma(
        const float* __restrict__ h, const __hip_bfloat16* __restrict__ Wcomb,
        __hip_bfloat16* __restrict__ feat, float* __restrict__ el,
        float* __restrict__ er) {
    __shared__ __hip_bfloat16 sbuf[4][16][136];   // 17408 B store staging
    const int t = threadIdx.x;
    const int lane = t & 63, wave = t >> 6;
    const int li = lane & 15, quad = lane >> 4;
    const int mt = blockIdx.x * 4 + wave;
    if (mt >= N_NODES / 16) return;               // 50000 = 16*3125
    const int m_base = mt * 16;
    bf16x8 a;
    {
        const float4* hp = (const float4*)(h + (size_t)(m_base + li) * 32 + quad * 8);
        const float4 f0 = hp[0], f1 = hp[1];
        a[0] = bfbits(f0.x); a[1] = bfbits(f0.y); a[2] = bfbits(f0.z); a[3] = bfbits(f0.w);
        a[4] = bfbits(f1.x); a[5] = bfbits(f1.y); a[6] = bfbits(f1.z); a[7] = bfbits(f1.w);
    }
    f32x4 acc[9];
#pragma unroll
    for (int j = 0; j < 9; ++j) acc[j] = (f32x4){0.f, 0.f, 0.f, 0.f};
#pragma unroll
    for (int j = 0; j < 9; ++j) {
        const bf16x8 b = *(const bf16x8*)(Wcomb + (size_t)(j * 16 + li) * 32 + quad * 8);
        acc[j] = __builtin_amdgcn_mfma_f32_16x16x32_bf16(a, b, acc[j], 0, 0, 0);
    }
#pragma unroll
    for (int j = 0; j < 8; ++j)
#pragma unroll
        for (int i = 0; i < 4; ++i)
            sbuf[wave][quad * 4 + i][j * 16 + li] = __float2bfloat16(acc[j][i]);
    __builtin_amdgcn_wave_barrier();
#pragma unroll
    for (int rep = 0; rep < 4; ++rep) {
        const int row = rep * 4 + quad;
        const bf16x8 v = *(const bf16x8*)(&sbuf[wave][row][li * 8]);
        *(bf16x8*)(feat + (size_t)(m_base + row) * 128 + li * 8) = v;
    }
    if (li < 8) {
#pragma unroll
        for (int i = 0; i < 4; ++i) {
            const int m = m_base + quad * 4 + i;
            if (li < 4) el[m * 4 + li] = acc[8][i];
            else        er[m * 4 + (li - 4)] = acc[8][i];
        }
    }
}

// ---------------------------------------------------------------------------
// K3: single-pass chained exclusive scan (decoupled lookback, 49 blocks all
// co-resident). counts -> offsets; offsets[N]=E.
// ---------------------------------------------------------------------------
__global__ __launch_bounds__(1024) void k_scan(
        const int* __restrict__ counts, int* __restrict__ offsets,
        int* __restrict__ flags, int* __restrict__ pref) {
    __shared__ int wtot[16];
    __shared__ int base_s;
    const int t = threadIdx.x;
    const int b = blockIdx.x;
    const int wave = t >> 6, lane = t & 63;
    const int idx = b * 1024 + t;
    const int v = (idx < N_NODES) ? counts[idx] : 0;
    int x = v;
#pragma unroll
    for (int m = 1; m < 64; m <<= 1) {
        const int y = __shfl_up(x, m, 64);
        if (lane >= m) x += y;
    }
    if (lane == 63) wtot[wave] = x;
    __syncthreads();
    if (t == 0) {
        int s = 0;
#pragma unroll
        for (int i = 0; i < 16; ++i) { const int tmp = wtot[i]; wtot[i] = s; s += tmp; }
        int base = 0;
        if (b > 0) {
            while (__hip_atomic_load(&flags[b - 1], __ATOMIC_ACQUIRE,
                                     __HIP_MEMORY_SCOPE_AGENT) == 0)
                __builtin_amdgcn_s_sleep(1);
            base = __hip_atomic_load(&pref[b - 1], __ATOMIC_RELAXED,
                                     __HIP_MEMORY_SCOPE_AGENT);
        }
        __hip_atomic_store(&pref[b], base + s, __ATOMIC_RELAXED,
                           __HIP_MEMORY_SCOPE_AGENT);
        __hip_atomic_store(&flags[b], 1, __ATOMIC_RELEASE,
                           __HIP_MEMORY_SCOPE_AGENT);
        base_s = base;
        if (b == SCAN_BLOCKS - 1) offsets[N_NODES] = N_EDGES;
    }
    __syncthreads();
    if (idx < N_NODES) offsets[idx] = base_s + wtot[wave] + x - v;
}

// ---------------------------------------------------------------------------
// K4: scatter src ids into dst-sorted order — atomic-free (offsets + rank)
// ---------------------------------------------------------------------------
__global__ __launch_bounds__(256) void k_scatter(
        const int* __restrict__ src, const int* __restrict__ dst,
        const int* __restrict__ offsets, const int* __restrict__ rank,
        int* __restrict__ srcs) {
    const int e = blockIdx.x * 256 + threadIdx.x;
    if (e < N_EDGES) srcs[offsets[dst[e]] + rank[e]] = src[e];
}

// ---------------------------------------------------------------------------
// K5 (fused aggr + GRU): block = 4 waves = 16 nodes = one GRU M-tile.
// Phase 1 (R6-proven): wave w aggregates nodes w*4..w*4+3 into LDS xh_tile;
//   batch-4 gather (VGPR-lean: occupancy is the BW lever here).
// Phase 2: waves 0/1 compute BOTH gi and gh for col block cb=wave (6 MFMA
//   tiles, 30 MFMAs) — epilogue is wave-local: no LDS exchange, one less sync.
// ---------------------------------------------------------------------------
__global__ __launch_bounds__(256) void k_aggr_gru(
        const int* __restrict__ offsets, const int* __restrict__ srcs,
        const __hip_bfloat16* __restrict__ feat,
        const float* __restrict__ el, const float* __restrict__ er,
        const float* __restrict__ h, const __hip_bfloat16* __restrict__ Wc,
        const float* __restrict__ bih, const float* __restrict__ bhh,
        float* __restrict__ out) {
    __shared__ __hip_bfloat16 xh_tile[16][160];   // 5 KB
    __shared__ int   sl_s[4][64];                 // 1 KB
    __shared__ float eel_s[4][256];               // 4 KB
    const int wave = threadIdx.x >> 6;
    const int lane = threadIdx.x & 63;
    int*   sl  = sl_s[wave];
    float* eel = eel_s[wave];
    const int hs = lane & 3;
    const int hc = lane >> 4;
    const int mbase = blockIdx.x * 16;

    // ---- phase 1: aggregate 4 nodes per wave ----
    for (int u = 0; u < 4; ++u) {
        const int row = wave * 4 + u;
        const int n = mbase + row;
        const float ern = er[n * 4 + hs];
        const int start = offsets[n], end = offsets[n + 1];
        float ax = 0.f, ay = 0.f, psum = 0.f;
        for (int chunk = start; chunk < end; chunk += 64) {
            const int cnt = min(64, end - chunk);
            if (lane < cnt) sl[lane] = srcs[chunk + lane];
            __builtin_amdgcn_wave_barrier();
#pragma unroll
            for (int p = 0; p < 4; ++p) {
                const int j = p * 64 + lane;       // j&3 == lane&3
                if (j < cnt * 4) {
                    const int s = sl[j >> 2];
                    float v = el[s * 4 + hs] + ern;
                    v = v > 0.f ? v : 0.2f * v;    // leaky_relu(0.2)
                    const float e = expf(v);
                    eel[j] = e;
                    psum += e;
                }
            }
            __builtin_amdgcn_wave_barrier();
            int i = 0;
            for (; i + 4 <= cnt; i += 4) {
                const int s0 = sl[i], s1 = sl[i + 1], s2 = sl[i + 2], s3 = sl[i + 3];
                const __hip_bfloat162 f0 = ((const __hip_bfloat162*)(feat + (size_t)s0 * 128))[lane];
                const __hip_bfloat162 f1 = ((const __hip_bfloat162*)(feat + (size_t)s1 * 128))[lane];
                const __hip_bfloat162 f2 = ((const __hip_bfloat162*)(feat + (size_t)s2 * 128))[lane];
                const __hip_bfloat162 f3 = ((const __hip_bfloat162*)(feat + (size_t)s3 * 128))[lane];
                const float w0 = eel[i * 4 + hc];
                const float w1 = eel[(i + 1) * 4 + hc];
                const float w2 = eel[(i + 2) * 4 + hc];
                const float w3 = eel[(i + 3) * 4 + hc];
                ax = fmaf(w0, __bfloat162float(f0.x), ax);
                ay = fmaf(w0, __bfloat162float(f0.y), ay);
                ax = fmaf(w1, __bfloat162float(f1.x), ax);
                ay = fmaf(w1, __bfloat162float(f1.y), ay);
                ax = fmaf(w2, __bfloat162float(f2.x), ax);
                ay = fmaf(w2, __bfloat162float(f2.y), ay);
                ax = fmaf(w3, __bfloat162float(f3.x), ax);
                ay = fmaf(w3, __bfloat162float(f3.y), ay);
            }
            for (; i < cnt; ++i) {
                const __hip_bfloat162 f = ((const __hip_bfloat162*)(feat + (size_t)sl[i] * 128))[lane];
                const float w = eel[i * 4 + hc];
                ax = fmaf(w, __bfloat162float(f.x), ax);
                ay = fmaf(w, __bfloat162float(f.y), ay);
            }
            __builtin_amdgcn_wave_barrier();
        }
#pragma unroll
        for (int m = 4; m < 64; m <<= 1) psum += __shfl_xor(psum, m, 64);
        const float dn = __shfl(psum, hc, 64);
        const float inv = (end > start) ? 1.f / dn : 0.f;
        __hip_bfloat162 v2;
        v2.x = __float2bfloat16(ax * inv);
        v2.y = __float2bfloat16(ay * inv);
        ((__hip_bfloat162*)&xh_tile[row][0])[lane] = v2;
        if (lane < 32) xh_tile[row][128 + lane] = __float2bfloat16(h[(size_t)n * 32 + lane]);
    }
    __syncthreads();

    // ---- phase 2: GRU MFMA, waves 0/1 only, fully wave-local ----
    if (wave < 2) {
        const int li = lane & 15, quad = lane >> 4;
        const int cb = wave;               // output col block (cols cb*16..+15)
        bf16x8 a[5];
#pragma unroll
        for (int s = 0; s < 5; ++s)
            a[s] = *(const bf16x8*)((const char*)&xh_tile[0][0] + li * 320 + s * 64 + quad * 16);
        f32x4 gi[3], gh[3];
#pragma unroll
        for (int g = 0; g < 3; ++g) {      // g: 0=r, 1=z, 2=n
            gi[g] = (f32x4){0.f, 0.f, 0.f, 0.f};
            gh[g] = (f32x4){0.f, 0.f, 0.f, 0.f};
            const int ji = g * 2 + cb;
            const int jh = 6 + g * 2 + cb;
            const bf16x8* bpi = (const bf16x8*)(Wc + (size_t)(ji * 16 + li) * 160 + quad * 8);
            const bf16x8* bph = (const bf16x8*)(Wc + (size_t)(jh * 16 + li) * 160 + quad * 8);
#pragma unroll
            for (int s = 0; s < 5; ++s) {
                gi[g] = __builtin_amdgcn_mfma_f32_16x16x32_bf16(a[s], bpi[s * 4], gi[g], 0, 0, 0);
                gh[g] = __builtin_amdgcn_mfma_f32_16x16x32_bf16(a[s], bph[s * 4], gh[g], 0, 0, 0);
            }
        }
        const int c = cb * 16 + li;
        const float bir = bih[c],      bhr = bhh[c];
        const float biz = bih[32 + c], bhz = bhh[32 + c];
        const float bin = bih[64 + c], bhn = bhh[64 + c];
#pragma unroll
        for (int i = 0; i < 4; ++i) {
            const int m = mbase + quad * 4 + i;
            const float gr = gi[0][i] + bir + gh[0][i] + bhr;
            const float gz = gi[1][i] + biz + gh[1][i] + bhz;
            const float r = 1.f / (1.f + expf(-gr));
            const float z = 1.f / (1.f + expf(-gz));
            const float nn = tanhf(gi[2][i] + bin + r * (gh[2][i] + bhn));
            const float hv = h[(size_t)m * 32 + c];
            const float hn = (1.f - z) * nn + z * hv;
            out[(size_t)m * 32 + c] = hn > 0.f ? hn : expm1f(hn);
        }
    }
}

extern "C" void kernel_launch(void* const* d_in, const int* in_sizes, int n_in,
                              void* d_out, int out_size, void* d_ws, size_t ws_size,
                              hipStream_t stream) {
    const float* h   = (const float*)d_in[0];
    const float* Wg  = (const float*)d_in[1];
    const float* al  = (const float*)d_in[2];
    const float* ar  = (const float*)d_in[3];
    const float* Wih = (const float*)d_in[4];
    const float* Whh = (const float*)d_in[5];
    const float* bih = (const float*)d_in[6];
    const float* bhh = (const float*)d_in[7];
    const int* src   = (const int*)d_in[8];
    const int* dst   = (const int*)d_in[9];
    float* out = (float*)d_out;

    // workspace layout (~21 MB)
    float* el = (float*)d_ws;                                 // N*4 f32
    float* er = el + (size_t)N_NODES * 4;                     // N*4 f32
    __hip_bfloat16* featb = (__hip_bfloat16*)(er + (size_t)N_NODES * 4); // N*128 bf16
    __hip_bfloat16* Wc    = featb + (size_t)N_NODES * 128;    // 192*160 bf16
    __hip_bfloat16* Wcomb = Wc + 192 * 160;                   // 144*32 bf16
    int* counts  = (int*)(Wcomb + PREP_WCB);                  // N
    int* flags   = counts + N_NODES;                          // 64
    int* pref    = flags + 64;                                // 64
    int* offsets = pref + 64;                                 // N+1
    int* srcs    = offsets + N_NODES + 1;                     // E
    int* rank    = srcs + N_EDGES;                            // E

    // zero counts + flags + pref in one shot
    hipMemsetAsync(counts, 0, (N_NODES + 128) * sizeof(int), stream);

    k_prep_hist<<<PREP_BLOCKS + HIST_BLOCKS, 256, 0, stream>>>(
        Wih, Whh, Wg, al, ar, dst, Wc, Wcomb, counts, rank);
    k_feat_mfma<<<(N_NODES / 16 + 3) / 4, 256, 0, stream>>>(
        h, Wcomb, featb, el, er);
    k_scan<<<SCAN_BLOCKS, 1024, 0, stream>>>(counts, offsets, flags, pref);
    k_scatter<<<(N_EDGES + 255) / 256, 256, 0, stream>>>(
        src, dst, offsets, rank, srcs);
    k_aggr_gru<<<N_NODES / 16, 256, 0, stream>>>(
        offsets, srcs, featb, el, er, h, Wc, bih, bhh, out);
}

// Round 9
// 190.368 us; speedup vs baseline: 1.4032x; 1.3685x over previous
//
#include <hip/hip_runtime.h>
#include <hip/hip_bf16.h>
#include <cmath>

#define N_NODES 50000
#define N_EDGES 800000

#define PREP_WC   (192 * 160)                 /* 30720 */
#define PREP_WCB  (144 * 32)                  /* 4608  */
#define PREP_ITEMS (PREP_WC + PREP_WCB)       /* 35328 */
#define PREP_BLOCKS ((PREP_ITEMS + 255) / 256)  /* 138 */
#define HIST_BLOCKS (N_EDGES / 256)           /* 3125 exact */
#define SCAN_BLOCKS 49                        /* ceil(50000/1024) */

typedef __attribute__((ext_vector_type(8))) short bf16x8;
typedef __attribute__((ext_vector_type(4))) float f32x4;

__device__ inline short bfbits(float x) {
    __hip_bfloat16 t = __float2bfloat16(x);
    return *reinterpret_cast<short*>(&t);
}

// ---------------------------------------------------------------------------
// K1 (fused prep + hist): blocks [0,138): build Wc (GRU B, 192x160 block-diag)
// and Wcomb (GAT B, 144x32). blocks [138,3263): histogram + per-edge rank.
// ---------------------------------------------------------------------------
__global__ __launch_bounds__(256) void k_prep_hist(
        const float* __restrict__ Wih, const float* __restrict__ Whh,
        const float* __restrict__ Wg, const float* __restrict__ al,
        const float* __restrict__ ar, const int* __restrict__ dst,
        __hip_bfloat16* __restrict__ Wc, __hip_bfloat16* __restrict__ Wcomb,
        int* __restrict__ counts, int* __restrict__ rank) {
    const int t = threadIdx.x;
    if (blockIdx.x >= PREP_BLOCKS) {
        const int e = (blockIdx.x - PREP_BLOCKS) * 256 + t;   // exact cover
        rank[e] = atomicAdd(&counts[dst[e]], 1);
        return;
    }
    int idx = blockIdx.x * 256 + t;
    if (idx < PREP_WC) {
        const int r = idx / 160, k = idx - r * 160;
        float v = 0.f;
        if (r < 96) { if (k < 128) v = Wih[r * 128 + k]; }
        else        { if (k >= 128) v = Whh[(r - 96) * 32 + (k - 128)]; }
        Wc[idx] = __float2bfloat16(v);
        return;
    }
    idx -= PREP_WC;
    if (idx < PREP_WCB) {
        const int row = idx >> 5, k = idx & 31;
        float v = 0.f;
        if (row < 128) {
            v = Wg[k * 128 + row];
        } else if (row < 136) {
            const int hd = (row - 128) & 3;
            const float* a = (row < 132) ? (al + hd * 32) : (ar + hd * 32);
            const float* w = Wg + k * 128 + hd * 32;
#pragma unroll
            for (int f = 0; f < 32; ++f) v = fmaf(w[f], a[f], v);
        }
        Wcomb[idx] = __float2bfloat16(v);
    }
}

// ---------------------------------------------------------------------------
// K2: GAT projection via MFMA. h converted f32->bf16 inline; feat stores
// staged via LDS -> dwordx4. Tiles 0..7 -> feat bf16; tile 8 -> el/er f32.
// ---------------------------------------------------------------------------
__global__ __launch_bounds__(256) void k_feat_mfma(
        const float* __restrict__ h, const __hip_bfloat16* __restrict__ Wcomb,
        __hip_bfloat16* __restrict__ feat, float* __restrict__ el,
        float* __restrict__ er) {
    __shared__ __hip_bfloat16 sbuf[4][16][136];   // 17408 B store staging
    const int t = threadIdx.x;
    const int lane = t & 63, wave = t >> 6;
    const int li = lane & 15, quad = lane >> 4;
    const int mt = blockIdx.x * 4 + wave;
    if (mt >= N_NODES / 16) return;               // 50000 = 16*3125
    const int m_base = mt * 16;
    bf16x8 a;
    {
        const float4* hp = (const float4*)(h + (size_t)(m_base + li) * 32 + quad * 8);
        const float4 f0 = hp[0], f1 = hp[1];
        a[0] = bfbits(f0.x); a[1] = bfbits(f0.y); a[2] = bfbits(f0.z); a[3] = bfbits(f0.w);
        a[4] = bfbits(f1.x); a[5] = bfbits(f1.y); a[6] = bfbits(f1.z); a[7] = bfbits(f1.w);
    }
    f32x4 acc[9];
#pragma unroll
    for (int j = 0; j < 9; ++j) acc[j] = (f32x4){0.f, 0.f, 0.f, 0.f};
#pragma unroll
    for (int j = 0; j < 9; ++j) {
        const bf16x8 b = *(const bf16x8*)(Wcomb + (size_t)(j * 16 + li) * 32 + quad * 8);
        acc[j] = __builtin_amdgcn_mfma_f32_16x16x32_bf16(a, b, acc[j], 0, 0, 0);
    }
#pragma unroll
    for (int j = 0; j < 8; ++j)
#pragma unroll
        for (int i = 0; i < 4; ++i)
            sbuf[wave][quad * 4 + i][j * 16 + li] = __float2bfloat16(acc[j][i]);
    __builtin_amdgcn_wave_barrier();
#pragma unroll
    for (int rep = 0; rep < 4; ++rep) {
        const int row = rep * 4 + quad;
        const bf16x8 v = *(const bf16x8*)(&sbuf[wave][row][li * 8]);
        *(bf16x8*)(feat + (size_t)(m_base + row) * 128 + li * 8) = v;
    }
    if (li < 8) {
#pragma unroll
        for (int i = 0; i < 4; ++i) {
            const int m = m_base + quad * 4 + i;
            if (li < 4) el[m * 4 + li] = acc[8][i];
            else        er[m * 4 + (li - 4)] = acc[8][i];
        }
    }
}

// ---------------------------------------------------------------------------
// K3a: per-1024-chunk exclusive scan + chunk sums (no cross-block waiting —
// the R7/R8 chained-lookback scan cost ~56 µs in serialized cross-XCD
// atomic hops; two small dispatches are far cheaper)
// ---------------------------------------------------------------------------
__global__ __launch_bounds__(1024) void k_scanA(
        const int* __restrict__ counts, int* __restrict__ offsets,
        int* __restrict__ bsums) {
    __shared__ int wtot[16];
    const int t = threadIdx.x;
    const int wave = t >> 6, lane = t & 63;
    const int idx = blockIdx.x * 1024 + t;
    const int v = (idx < N_NODES) ? counts[idx] : 0;
    int x = v;
#pragma unroll
    for (int m = 1; m < 64; m <<= 1) {
        const int y = __shfl_up(x, m, 64);
        if (lane >= m) x += y;
    }
    if (lane == 63) wtot[wave] = x;
    __syncthreads();
    if (t == 0) {
        int s = 0;
#pragma unroll
        for (int i = 0; i < 16; ++i) { const int tmp = wtot[i]; wtot[i] = s; s += tmp; }
        bsums[blockIdx.x] = s;
    }
    __syncthreads();
    if (idx < N_NODES) offsets[idx] = wtot[wave] + x - v;
}

// ---------------------------------------------------------------------------
// K3b: add chunk base (each block re-derives its prefix of the 49 bsums with
// one 64-lane shuffle reduction); writes offsets[N]=E.
// ---------------------------------------------------------------------------
__global__ __launch_bounds__(1024) void k_scanC(
        int* __restrict__ offsets, const int* __restrict__ bsums) {
    __shared__ int base_s;
    const int t = threadIdx.x;
    if (t < 64) {
        int v = (t < (int)blockIdx.x) ? bsums[t] : 0;   // blockIdx < 49 <= 64
#pragma unroll
        for (int m = 1; m < 64; m <<= 1) v += __shfl_xor(v, m, 64);
        if (t == 0) base_s = v;
    }
    __syncthreads();
    const int idx = blockIdx.x * 1024 + t;
    if (idx < N_NODES) offsets[idx] += base_s;
    if (blockIdx.x == 0 && t == 0) offsets[N_NODES] = N_EDGES;
}

// ---------------------------------------------------------------------------
// K4: scatter src ids into dst-sorted order — atomic-free (offsets + rank)
// ---------------------------------------------------------------------------
__global__ __launch_bounds__(256) void k_scatter(
        const int* __restrict__ src, const int* __restrict__ dst,
        const int* __restrict__ offsets, const int* __restrict__ rank,
        int* __restrict__ srcs) {
    const int e = blockIdx.x * 256 + threadIdx.x;
    if (e < N_EDGES) srcs[offsets[dst[e]] + rank[e]] = src[e];
}

// ---------------------------------------------------------------------------
// K5 (fused aggr + GRU) — R6-proven shape (VGPR 36, 56.6 µs measured):
// Phase 1: wave w aggregates nodes w*4..w*4+3 into LDS xh_tile (batch-4).
// Phase 2: 12 gate-tiles split 3-per-wave; gh waves exchange via LDS.
// ---------------------------------------------------------------------------
__global__ __launch_bounds__(256) void k_aggr_gru(
        const int* __restrict__ offsets, const int* __restrict__ srcs,
        const __hip_bfloat16* __restrict__ feat,
        const float* __restrict__ el, const float* __restrict__ er,
        const float* __restrict__ h, const __hip_bfloat16* __restrict__ Wc,
        const float* __restrict__ bih, const float* __restrict__ bhh,
        float* __restrict__ out) {
    __shared__ __hip_bfloat16 xh_tile[16][160];   // 5 KB
    __shared__ int   sl_s[4][64];                 // 1 KB
    __shared__ float eel_s[4][256];               // 4 KB
    __shared__ float ex[2][3][16][16];            // 6 KB gh exchange
    const int wave = threadIdx.x >> 6;
    const int lane = threadIdx.x & 63;
    int*   sl  = sl_s[wave];
    float* eel = eel_s[wave];
    const int hs = lane & 3;
    const int hc = lane >> 4;
    const int mbase = blockIdx.x * 16;

    // ---- phase 1: aggregate 4 nodes per wave ----
    for (int u = 0; u < 4; ++u) {
        const int row = wave * 4 + u;
        const int n = mbase + row;
        const float ern = er[n * 4 + hs];
        const int start = offsets[n], end = offsets[n + 1];
        float ax = 0.f, ay = 0.f, psum = 0.f;
        for (int chunk = start; chunk < end; chunk += 64) {
            const int cnt = min(64, end - chunk);
            if (lane < cnt) sl[lane] = srcs[chunk + lane];
            __builtin_amdgcn_wave_barrier();
#pragma unroll
            for (int p = 0; p < 4; ++p) {
                const int j = p * 64 + lane;       // j&3 == lane&3
                if (j < cnt * 4) {
                    const int s = sl[j >> 2];
                    float v = el[s * 4 + hs] + ern;
                    v = v > 0.f ? v : 0.2f * v;    // leaky_relu(0.2)
                    const float e = expf(v);
                    eel[j] = e;
                    psum += e;
                }
            }
            __builtin_amdgcn_wave_barrier();
            int i = 0;
            for (; i + 4 <= cnt; i += 4) {
                const int s0 = sl[i], s1 = sl[i + 1], s2 = sl[i + 2], s3 = sl[i + 3];
                const __hip_bfloat162 f0 = ((const __hip_bfloat162*)(feat + (size_t)s0 * 128))[lane];
                const __hip_bfloat162 f1 = ((const __hip_bfloat162*)(feat + (size_t)s1 * 128))[lane];
                const __hip_bfloat162 f2 = ((const __hip_bfloat162*)(feat + (size_t)s2 * 128))[lane];
                const __hip_bfloat162 f3 = ((const __hip_bfloat162*)(feat + (size_t)s3 * 128))[lane];
                const float w0 = eel[i * 4 + hc];
                const float w1 = eel[(i + 1) * 4 + hc];
                const float w2 = eel[(i + 2) * 4 + hc];
                const float w3 = eel[(i + 3) * 4 + hc];
                ax = fmaf(w0, __bfloat162float(f0.x), ax);
                ay = fmaf(w0, __bfloat162float(f0.y), ay);
                ax = fmaf(w1, __bfloat162float(f1.x), ax);
                ay = fmaf(w1, __bfloat162float(f1.y), ay);
                ax = fmaf(w2, __bfloat162float(f2.x), ax);
                ay = fmaf(w2, __bfloat162float(f2.y), ay);
                ax = fmaf(w3, __bfloat162float(f3.x), ax);
                ay = fmaf(w3, __bfloat162float(f3.y), ay);
            }
            for (; i < cnt; ++i) {
                const __hip_bfloat162 f = ((const __hip_bfloat162*)(feat + (size_t)sl[i] * 128))[lane];
                const float w = eel[i * 4 + hc];
                ax = fmaf(w, __bfloat162float(f.x), ax);
                ay = fmaf(w, __bfloat162float(f.y), ay);
            }
            __builtin_amdgcn_wave_barrier();
        }
#pragma unroll
        for (int m = 4; m < 64; m <<= 1) psum += __shfl_xor(psum, m, 64);
        const float dn = __shfl(psum, hc, 64);
        const float inv = (end > start) ? 1.f / dn : 0.f;
        __hip_bfloat162 v2;
        v2.x = __float2bfloat16(ax * inv);
        v2.y = __float2bfloat16(ay * inv);
        ((__hip_bfloat162*)&xh_tile[row][0])[lane] = v2;
        if (lane < 32) xh_tile[row][128 + lane] = __float2bfloat16(h[(size_t)n * 32 + lane]);
    }
    __syncthreads();

    // ---- phase 2: GRU MFMA, 3 tiles per wave, gh exchange via LDS ----
    const int li = lane & 15, quad = lane >> 4;
    const int cb = wave >> 1;          // output col block
    const int ghrole = wave & 1;       // 0: gi tiles, 1: gh tiles
    bf16x8 a[5];
#pragma unroll
    for (int s = 0; s < 5; ++s)
        a[s] = *(const bf16x8*)((const char*)&xh_tile[0][0] + li * 320 + s * 64 + quad * 16);
    f32x4 acc[3];
#pragma unroll
    for (int g = 0; g < 3; ++g) {      // g: 0=r, 1=z, 2=n
        acc[g] = (f32x4){0.f, 0.f, 0.f, 0.f};
        const int j = g * 2 + cb + ghrole * 6;
        const bf16x8* bp = (const bf16x8*)(Wc + (size_t)(j * 16 + li) * 160 + quad * 8);
        acc[g] = __builtin_amdgcn_mfma_f32_16x16x32_bf16(a[0], bp[0],  acc[g], 0, 0, 0);
        acc[g] = __builtin_amdgcn_mfma_f32_16x16x32_bf16(a[1], bp[4],  acc[g], 0, 0, 0);
        acc[g] = __builtin_amdgcn_mfma_f32_16x16x32_bf16(a[2], bp[8],  acc[g], 0, 0, 0);
        acc[g] = __builtin_amdgcn_mfma_f32_16x16x32_bf16(a[3], bp[12], acc[g], 0, 0, 0);
        acc[g] = __builtin_amdgcn_mfma_f32_16x16x32_bf16(a[4], bp[16], acc[g], 0, 0, 0);
    }
    if (ghrole) {
#pragma unroll
        for (int g = 0; g < 3; ++g)
#pragma unroll
            for (int i = 0; i < 4; ++i)
                ex[cb][g][quad * 4 + i][li] = acc[g][i];
    }
    __syncthreads();
    if (!ghrole) {
        const int c = cb * 16 + li;
        const float bir = bih[c],      bhr = bhh[c];
        const float biz = bih[32 + c], bhz = bhh[32 + c];
        const float bin = bih[64 + c], bhn = bhh[64 + c];
#pragma unroll
        for (int i = 0; i < 4; ++i) {
            const int row = quad * 4 + i;
            const int m = mbase + row;
            const float gr = acc[0][i] + bir + ex[cb][0][row][li] + bhr;
            const float gz = acc[1][i] + biz + ex[cb][1][row][li] + bhz;
            const float r = 1.f / (1.f + expf(-gr));
            const float z = 1.f / (1.f + expf(-gz));
            const float nn = tanhf(acc[2][i] + bin + r * (ex[cb][2][row][li] + bhn));
            const float hv = h[(size_t)m * 32 + c];
            const float hn = (1.f - z) * nn + z * hv;
            out[(size_t)m * 32 + c] = hn > 0.f ? hn : expm1f(hn);
        }
    }
}

extern "C" void kernel_launch(void* const* d_in, const int* in_sizes, int n_in,
                              void* d_out, int out_size, void* d_ws, size_t ws_size,
                              hipStream_t stream) {
    const float* h   = (const float*)d_in[0];
    const float* Wg  = (const float*)d_in[1];
    const float* al  = (const float*)d_in[2];
    const float* ar  = (const float*)d_in[3];
    const float* Wih = (const float*)d_in[4];
    const float* Whh = (const float*)d_in[5];
    const float* bih = (const float*)d_in[6];
    const float* bhh = (const float*)d_in[7];
    const int* src   = (const int*)d_in[8];
    const int* dst   = (const int*)d_in[9];
    float* out = (float*)d_out;

    // workspace layout (~21 MB)
    float* el = (float*)d_ws;                                 // N*4 f32
    float* er = el + (size_t)N_NODES * 4;                     // N*4 f32
    __hip_bfloat16* featb = (__hip_bfloat16*)(er + (size_t)N_NODES * 4); // N*128 bf16
    __hip_bfloat16* Wc    = featb + (size_t)N_NODES * 128;    // 192*160 bf16
    __hip_bfloat16* Wcomb = Wc + 192 * 160;                   // 144*32 bf16
    int* counts  = (int*)(Wcomb + PREP_WCB);                  // N
    int* offsets = counts + N_NODES;                          // N+1
    int* srcs    = offsets + N_NODES + 1;                     // E
    int* rank    = srcs + N_EDGES;                            // E
    int* bsums   = rank + N_EDGES;                            // 49

    hipMemsetAsync(counts, 0, N_NODES * sizeof(int), stream);

    k_prep_hist<<<PREP_BLOCKS + HIST_BLOCKS, 256, 0, stream>>>(
        Wih, Whh, Wg, al, ar, dst, Wc, Wcomb, counts, rank);
    k_feat_mfma<<<(N_NODES / 16 + 3) / 4, 256, 0, stream>>>(
        h, Wcomb, featb, el, er);
    k_scanA<<<SCAN_BLOCKS, 1024, 0, stream>>>(counts, offsets, bsums);
    k_scanC<<<SCAN_BLOCKS, 1024, 0, stream>>>(offsets, bsums);
    k_scatter<<<(N_EDGES + 255) / 256, 256, 0, stream>>>(
        src, dst, offsets, rank, srcs);
    k_aggr_gru<<<N_NODES / 16, 256, 0, stream>>>(
        offsets, srcs, featb, el, er, h, Wc, bih, bhh, out);
}